// Round 12
// baseline (484.140 us; speedup 1.0000x reference)
//
#include <hip/hip_runtime.h>

typedef unsigned short u16;
typedef unsigned int   u32;
typedef unsigned char  u8;
typedef __attribute__((ext_vector_type(4))) int   i32x4;

constexpr int B_ = 4, S_ = 4096, DIN_ = 2048, DOUT_ = 8192;
constexpr int M_ = B_ * S_;   // 16384
constexpr int N_ = DOUT_;     // 8192
constexpr int K_ = DIN_;      // 2048
constexpr size_t NW_ = (size_t)DOUT_ * DIN_;  // 16,777,216 weights

#define GPTR(p) ((const __attribute__((address_space(1))) void*)(p))
#define LPTR(p) ((__attribute__((address_space(3))) void*)(p))

#define SB0()   __builtin_amdgcn_sched_barrier(0)
#define BAR()   asm volatile("s_barrier" ::: "memory")
#define LGKM0() asm volatile("s_waitcnt lgkmcnt(0)" ::: "memory")
#define VM4()   asm volatile("s_waitcnt vmcnt(4)" ::: "memory")
#define VM0()   asm volatile("s_waitcnt vmcnt(0)" ::: "memory")

// ---------------------------------------------------------------------------
// Pass 1: deterministic fp64 abs-sum partials.
// ---------------------------------------------------------------------------
__global__ __launch_bounds__(256)
void abssum_kernel(const float* __restrict__ w, double* __restrict__ partials)
{
    const int tid = threadIdx.x;
    const float* base = w + (size_t)blockIdx.x * 16384 + tid * 4;
    double s = 0.0;
#pragma unroll
    for (int i = 0; i < 16; ++i) {
        float4 v = *(const float4*)(base + i * 1024);
        s += (double)fabsf(v.x) + (double)fabsf(v.y)
           + (double)fabsf(v.z) + (double)fabsf(v.w);
    }
#pragma unroll
    for (int o = 32; o; o >>= 1) s += __shfl_xor(s, o, 64);
    __shared__ double red[4];
    if ((tid & 63) == 0) red[tid >> 6] = s;
    __syncthreads();
    if (tid == 0) partials[blockIdx.x] = (red[0] + red[1]) + (red[2] + red[3]);
}

__global__ __launch_bounds__(1024)
void finalize_thr(const double* __restrict__ partials, double* __restrict__ thr)
{
    __shared__ double red[1024];
    const int tid = threadIdx.x;
    red[tid] = partials[tid];
    __syncthreads();
    for (int s = 512; s > 0; s >>= 1) {
        if (tid < s) red[tid] += red[tid + s];
        __syncthreads();
    }
    if (tid == 0) *thr = red[0] * (1.0 / (double)NW_);
}

// ---------------------------------------------------------------------------
// Merged prep: blocks [0,M): RMSNorm row -> i8 + per-row scale;
//              blocks [M, M+16384): ternarize W chunk -> i8 {-1,0,+1}.
// Both after finalize_thr (ternarize needs thr; rmsnorm independent).
// ---------------------------------------------------------------------------
__global__ __launch_bounds__(256)
void prep_kernel(const float* __restrict__ x, const float* __restrict__ gamma,
                 const double* __restrict__ thr_p, const float* __restrict__ w,
                 signed char* __restrict__ wt,
                 signed char* __restrict__ xn, float* __restrict__ scale)
{
    __shared__ float redsum[4];
    __shared__ float redmax[4];
    const int tid = threadIdx.x;

    if (blockIdx.x >= (unsigned)M_) {
        // ---- ternarize path (uniform per block; fp64 compare: threshold razor-thin) ----
        const double thr = *thr_p;
        const size_t i = ((size_t)(blockIdx.x - M_) * 256 + tid) * 4;
        float4 v = *(const float4*)(w + i);
        union { signed char c[4]; u32 u; } p;
        p.c[0] = (signed char)((fabs((double)v.x) > thr) ? (v.x > 0.0f ? 1 : -1) : 0);
        p.c[1] = (signed char)((fabs((double)v.y) > thr) ? (v.y > 0.0f ? 1 : -1) : 0);
        p.c[2] = (signed char)((fabs((double)v.z) > thr) ? (v.z > 0.0f ? 1 : -1) : 0);
        p.c[3] = (signed char)((fabs((double)v.w) > thr) ? (v.w > 0.0f ? 1 : -1) : 0);
        *(u32*)(wt + i) = p.u;
        return;
    }

    // ---- RMSNorm + i8 quant path ----
    const int row = blockIdx.x;
    const float* xr = x + (size_t)row * K_;
    float4 a = *(const float4*)(xr + tid * 8);
    float4 b = *(const float4*)(xr + tid * 8 + 4);
    float s = a.x*a.x + a.y*a.y + a.z*a.z + a.w*a.w
            + b.x*b.x + b.y*b.y + b.z*b.z + b.w*b.w;
#pragma unroll
    for (int o = 32; o; o >>= 1) s += __shfl_xor(s, o, 64);
    if ((tid & 63) == 0) redsum[tid >> 6] = s;
    __syncthreads();
    const float tot = (redsum[0] + redsum[1]) + (redsum[2] + redsum[3]);
    const float r = rsqrtf(tot * (1.0f / (float)K_) + 1.1920928955078125e-07f);
    float4 g0 = *(const float4*)(gamma + tid * 8);
    float4 g1 = *(const float4*)(gamma + tid * 8 + 4);
    float v[8];
    v[0] = a.x * r * g0.x;  v[1] = a.y * r * g0.y;
    v[2] = a.z * r * g0.z;  v[3] = a.w * r * g0.w;
    v[4] = b.x * r * g1.x;  v[5] = b.y * r * g1.y;
    v[6] = b.z * r * g1.z;  v[7] = b.w * r * g1.w;
    float m = 0.0f;
#pragma unroll
    for (int j = 0; j < 8; ++j) m = fmaxf(m, fabsf(v[j]));
#pragma unroll
    for (int o = 32; o; o >>= 1) m = fmaxf(m, __shfl_xor(m, o, 64));
    if ((tid & 63) == 0) redmax[tid >> 6] = m;
    __syncthreads();
    const float rowmax = fmaxf(fmaxf(redmax[0], redmax[1]), fmaxf(redmax[2], redmax[3]));
    const float inv = rowmax > 0.0f ? 127.0f / rowmax : 0.0f;
    union { signed char c[8]; uint2 u; } p;
#pragma unroll
    for (int j = 0; j < 8; ++j) p.c[j] = (signed char)__float2int_rn(v[j] * inv);
    *(uint2*)(xn + (size_t)row * K_ + tid * 8) = p.u;
    if (tid == 0) scale[row] = rowmax * (1.0f / 127.0f);
}

// ---------------------------------------------------------------------------
// Pass 5: GEMM  C[M,N] = scale[m] * (xn_i8[M,K] @ wt_i8[N,K]^T) + bias
// v12: 128x128 tile, BK=128, 4 waves (2Mx2N, each 64x64 out), 64 KiB LDS ->
// TWO blocks co-resident per CU (two independent barrier domains). Block A's
// LDS-drain/barrier-wait overlaps block B's MFMA cluster — breaking the CU-
// level LDS<->MFMA serialization that pinned v2..v11 at 35-43% MfmaUtil.
// Same zero-conflict swizzle (rows=lane&15, 128B rows) and phase discipline
// as v11, scaled: iteration = 2 K-tiles of 128 (buf0@kt0=256i, buf1@kt1).
//
//   phase: reads          stage (2 gloads)            MFMA (8x 16x16x64 i8)
//   p0   : a0,b0 (buf0)   B1 j01 -> Bbuf1@kt1         Q0 = m01 x n01
//   p1   : a1    (buf0)   B1 j23 -> Bbuf1@kt1         Q2 = m23 x n01
//   p2   : b1    (buf0)   A0 j01 -> Abuf0@ktn0  [f]   Q1 = m01 x n23
//   p3   : --             A0 j23 -> Abuf0@ktn0  [f]   Q3 = m23 x n23  VM4*
//   p4-7 : same on buf1 (B0 -> Bbuf0@ktn0, A1 -> Abuf1@ktn1)          VM4*
// Phase body: [reads|stage] BAR lgkm0 setprio1 MFMA setprio0 [VM*] BAR.
// vmcnt ledger (gloads/thread): each VM4 sees 12 outstanding, retires the 8
// covering the buffer read next (staged 4-7 phases earlier). Prologue 12->4.
// Tail i=7: p0/p1 B1@1920 still staged; p3 VM0; p4-p7 stage nothing.
// WAR: restage of a region is >=1 full phase after the lgkm0+BAR retiring
// the last read of that region (same argument as v9/v11, verified passing).
// ---------------------------------------------------------------------------
__global__ __launch_bounds__(256, 2)
void gemm_bt_kernel(const u8* __restrict__ A, const u8* __restrict__ Bt,
                    const float* __restrict__ bias, const float* __restrict__ scale,
                    float* __restrict__ C)
{
    __shared__ alignas(16) u8 sm[65536];   // A[2][128][128B] @0 | B[2][128][128B] @32768
    const char* smc = (const char*)sm;

    const int tid  = threadIdx.x;
    const int lane = tid & 63;
    const int wid  = tid >> 6;         // 0..3
    const int wm   = wid >> 1;         // 0..1
    const int wn   = wid & 1;          // 0..1
    const int hi   = lane >> 4;        // 0..3

    // XCD-aware bijective swizzle: 8192 blocks % 8 == 0 -> 1024/XCD
    const int swz = (blockIdx.x & 7) * 1024 + (blockIdx.x >> 3);
    const int gm0 = (swz >> 6) * 128;  // 128 M-tiles
    const int gn0 = (swz & 63) * 128;  // 64 N-tiles

    // ---- staging geometry (linear LDS dest, pre-swizzled global source) ----
    // LDS 16B-unit u = j*256 + tid: row = u>>3, slot = tid&7; content k-slot
    // = slot ^ (row&7)  (row&7 == (tid>>3)&7 since j steps by 32 rows).
    const int cswel = ((tid & 7) ^ ((tid >> 3) & 7)) * 16;
    const u8* gA = A  + (size_t)(gm0 + (tid >> 3)) * K_ + cswel;
    const u8* gB = Bt + (size_t)(gn0 + (tid >> 3)) * K_ + cswel;

    // 2 gloads covering rows [j*32, (j+2)*32)
    auto STAGE2 = [&](const u8* g, int ldsb, int kt, int j) {
        u8* d = sm + ldsb + j * 4096 + tid * 16;
        const u8* s = g + (size_t)j * 32 * K_ + kt;
        __builtin_amdgcn_global_load_lds(GPTR(s),                   LPTR(d),        16, 0, 0);
        __builtin_amdgcn_global_load_lds(GPTR(s + (size_t)32 * K_), LPTR(d + 4096), 16, 0, 0);
    };
#define ABUF(b) ((b) * 16384)
#define BBUF(b) (32768 + (b) * 16384)

    // ---- read geometry (v9/v11 zero-conflict pattern) ----
    const int c0 = ((hi ^ (lane & 7)) << 4);
    const int rowbyteA = (wm * 64 + (lane & 15)) * 128;
    const int rowbyteB = (wn * 64 + (lane & 15)) * 128;

#define RA(bufr, m, kk) (*(const i32x4*)(smc + (bufr)*16384 + rowbyteA + (m)*2048 + (c0 ^ ((kk) << 6))))
#define RB(bufr, n, kk) (*(const i32x4*)(smc + 32768 + (bufr)*16384 + rowbyteB + (n)*2048 + (c0 ^ ((kk) << 6))))

    i32x4 acc[4][4] = {};
    i32x4 a0[2][2], a1[2][2], b0[2][2], b1[2][2];

#define MFMA_BLK(AF, BF, MO, NO)                                                   \
    do {                                                                           \
        _Pragma("unroll") for (int kk = 0; kk < 2; ++kk)                           \
        _Pragma("unroll") for (int m = 0; m < 2; ++m)                              \
        _Pragma("unroll") for (int n = 0; n < 2; ++n)                              \
            acc[m + MO][n + NO] = __builtin_amdgcn_mfma_i32_16x16x64_i8(           \
                AF[m][kk], BF[n][kk], acc[m + MO][n + NO], 0, 0, 0);               \
    } while (0)

#define READ_A0B0(bufr)                                                            \
    do {                                                                           \
        _Pragma("unroll") for (int m = 0; m < 2; ++m) {                            \
            a0[m][0] = RA(bufr, m, 0); a0[m][1] = RA(bufr, m, 1); }                \
        _Pragma("unroll") for (int n = 0; n < 2; ++n) {                            \
            b0[n][0] = RB(bufr, n, 0); b0[n][1] = RB(bufr, n, 1); }                \
    } while (0)
#define READ_A1(bufr)                                                              \
    do { _Pragma("unroll") for (int m = 0; m < 2; ++m) {                           \
            a1[m][0] = RA(bufr, m + 2, 0); a1[m][1] = RA(bufr, m + 2, 1); } } while (0)
#define READ_B1(bufr)                                                              \
    do { _Pragma("unroll") for (int n = 0; n < 2; ++n) {                           \
            b1[n][0] = RB(bufr, n + 2, 0); b1[n][1] = RB(bufr, n + 2, 1); } } while (0)

#define PRIO_MFMA(AF, BF, MO, NO)                                                  \
    do { __builtin_amdgcn_s_setprio(1); MFMA_BLK(AF, BF, MO, NO);                  \
         __builtin_amdgcn_s_setprio(0); } while (0)

    // ---- prologue: A0,B0 @k0 (8 gloads), A1 @k128 (4); retire buf0 ----
    STAGE2(gA, ABUF(0), 0, 0);   STAGE2(gA, ABUF(0), 0, 2);
    STAGE2(gB, BBUF(0), 0, 0);   STAGE2(gB, BBUF(0), 0, 2);
    STAGE2(gA, ABUF(1), 128, 0); STAGE2(gA, ABUF(1), 128, 2);
    VM4(); SB0(); BAR();

    for (int i = 0; i < 8; ++i) {
        const int kt1  = i * 256 + 128;
        const int ktn0 = i * 256 + 256;
        const int ktn1 = i * 256 + 384;
        const bool f = (i < 7);

        // ---- p0 ----
        READ_A0B0(0);
        STAGE2(gB, BBUF(1), kt1, 0);
        SB0(); BAR(); LGKM0(); SB0();
        PRIO_MFMA(a0, b0, 0, 0);
        SB0(); BAR();

        // ---- p1 ----
        READ_A1(0);
        STAGE2(gB, BBUF(1), kt1, 2);
        SB0(); BAR(); LGKM0(); SB0();
        PRIO_MFMA(a1, b0, 2, 0);
        SB0(); BAR();

        // ---- p2 ----
        READ_B1(0);
        if (f) STAGE2(gA, ABUF(0), ktn0, 0);
        SB0(); BAR(); LGKM0(); SB0();
        PRIO_MFMA(a0, b1, 0, 2);
        SB0(); BAR();

        // ---- p3 ----
        if (f) STAGE2(gA, ABUF(0), ktn0, 2);
        SB0(); BAR();
        PRIO_MFMA(a1, b1, 2, 2);
        SB0();
        if (f) { VM4(); } else { VM0(); }
        SB0(); BAR();

        // ---- p4 ----
        READ_A0B0(1);
        if (f) STAGE2(gB, BBUF(0), ktn0, 0);
        SB0(); BAR(); LGKM0(); SB0();
        PRIO_MFMA(a0, b0, 0, 0);
        SB0(); BAR();

        // ---- p5 ----
        READ_A1(1);
        if (f) STAGE2(gB, BBUF(0), ktn0, 2);
        SB0(); BAR(); LGKM0(); SB0();
        PRIO_MFMA(a1, b0, 2, 0);
        SB0(); BAR();

        // ---- p6 ----
        READ_B1(1);
        if (f) STAGE2(gA, ABUF(1), ktn1, 0);
        SB0(); BAR(); LGKM0(); SB0();
        PRIO_MFMA(a0, b1, 0, 2);
        SB0(); BAR();

        // ---- p7 ----
        if (f) STAGE2(gA, ABUF(1), ktn1, 2);
        SB0(); BAR();
        PRIO_MFMA(a1, b1, 2, 2);
        SB0();
        if (f) { VM4(); }
        SB0(); BAR();
    }

    // ---- epilogue: C/D col=lane&15, row=hi*4+ri; dequant + bias ----
    const int orow0 = gm0 + wm * 64 + hi * 4;
    const int ocol0 = gn0 + wn * 64 + (lane & 15);
    float bv[4];
#pragma unroll
    for (int n = 0; n < 4; ++n) bv[n] = bias[ocol0 + n * 16];
#pragma unroll
    for (int m = 0; m < 4; ++m) {
#pragma unroll
        for (int ri = 0; ri < 4; ++ri) {
            const int row = orow0 + m * 16 + ri;
            const float sc = scale[row];
#pragma unroll
            for (int n = 0; n < 4; ++n) {
                C[(size_t)row * N_ + (ocol0 + n * 16)] = (float)acc[m][n][ri] * sc + bv[n];
            }
        }
    }
#undef RA
#undef RB
#undef MFMA_BLK
#undef READ_A0B0
#undef READ_A1
#undef READ_B1
#undef PRIO_MFMA
#undef ABUF
#undef BBUF
}

// ---------------------------------------------------------------------------
// Workspace layout (bytes):
//   [0,8)                    : thr (double)
//   [1024, 9216)             : 1024 fp64 partials
//   [16384, +16MiB)          : wt    i8 [N=8192][K=2048]
//   [+16MiB, +48MiB)         : xn    i8 [M=16384][K=2048]
//   [+48MiB, +48MiB+64KiB)   : scale f32 [M]
// ---------------------------------------------------------------------------
extern "C" void kernel_launch(void* const* d_in, const int* in_sizes, int n_in,
                              void* d_out, int out_size, void* d_ws, size_t ws_size,
                              hipStream_t stream)
{
    const float* x     = (const float*)d_in[0];
    const float* w     = (const float*)d_in[1];
    const float* bias  = (const float*)d_in[2];
    const float* gamma = (const float*)d_in[3];
    float* out = (float*)d_out;

    char* ws = (char*)d_ws;
    double*      thr      = (double*)(ws);
    double*      partials = (double*)(ws + 1024);
    signed char* wt       = (signed char*)(ws + 16384);
    signed char* xn       = (signed char*)(ws + 16384 + NW_);
    float*       scale    = (float*)(ws + 16384 + NW_ + (size_t)M_ * K_);

    abssum_kernel <<<1024,  256,  0, stream>>>(w, partials);
    finalize_thr  <<<1,     1024, 0, stream>>>(partials, thr);
    prep_kernel   <<<M_ + 16384, 256, 0, stream>>>(x, gamma, thr, w, wt, xn, scale);
    gemm_bt_kernel<<<(M_/128)*(N_/128), 256, 0, stream>>>((const u8*)xn, (const u8*)wt, bias, scale, out);
}

// Round 13
// 475.252 us; speedup vs baseline: 1.0187x; 1.0187x over previous
//
#include <hip/hip_runtime.h>

typedef unsigned short u16;
typedef unsigned int   u32;
typedef unsigned char  u8;
typedef __attribute__((ext_vector_type(4))) int   i32x4;

constexpr int B_ = 4, S_ = 4096, DIN_ = 2048, DOUT_ = 8192;
constexpr int M_ = B_ * S_;   // 16384
constexpr int N_ = DOUT_;     // 8192
constexpr int K_ = DIN_;      // 2048
constexpr size_t NW_ = (size_t)DOUT_ * DIN_;  // 16,777,216 weights

// ---------------------------------------------------------------------------
// Pass 1: deterministic fp64 abs-sum partials.
// ---------------------------------------------------------------------------
__global__ __launch_bounds__(256)
void abssum_kernel(const float* __restrict__ w, double* __restrict__ partials)
{
    const int tid = threadIdx.x;
    const float* base = w + (size_t)blockIdx.x * 16384 + tid * 4;
    double s = 0.0;
#pragma unroll
    for (int i = 0; i < 16; ++i) {
        float4 v = *(const float4*)(base + i * 1024);
        s += (double)fabsf(v.x) + (double)fabsf(v.y)
           + (double)fabsf(v.z) + (double)fabsf(v.w);
    }
#pragma unroll
    for (int o = 32; o; o >>= 1) s += __shfl_xor(s, o, 64);
    __shared__ double red[4];
    if ((tid & 63) == 0) red[tid >> 6] = s;
    __syncthreads();
    if (tid == 0) partials[blockIdx.x] = (red[0] + red[1]) + (red[2] + red[3]);
}

__global__ __launch_bounds__(1024)
void finalize_thr(const double* __restrict__ partials, double* __restrict__ thr)
{
    __shared__ double red[1024];
    const int tid = threadIdx.x;
    red[tid] = partials[tid];
    __syncthreads();
    for (int s = 512; s > 0; s >>= 1) {
        if (tid < s) red[tid] += red[tid + s];
        __syncthreads();
    }
    if (tid == 0) *thr = red[0] * (1.0 / (double)NW_);
}

// ---------------------------------------------------------------------------
// prep_w: ternarize W -> i8 {-1,0,+1} stored in MFMA-FRAGMENT-DIRECT layout:
//   B'[g][kt][lane][16] : lane = hi*16 + (row&15) holds rows g*16+(row&15),
//   k = kt*64 + hi*16 + j  (exactly the 16x16x64 i8 B-fragment, per v11).
// Block = one 16-row group g, all K. Reads coalesced (256B/lr-group/iter);
// LDS bounce; output writes fully coalesced (16B x consecutive lanes).
// fp64 threshold compare (razor-thin).
// ---------------------------------------------------------------------------
__global__ __launch_bounds__(256)
void prep_w_kernel(const float* __restrict__ w, const double* __restrict__ thr_p,
                   u8* __restrict__ Bp)
{
    __shared__ alignas(16) signed char xs[16][2064];   // +16B pad: 2-way banks (free)
    const int tid = threadIdx.x;
    const int g   = blockIdx.x;        // 512 groups
    const int lr  = tid >> 4;          // 0..15 row-in-group
    const int c   = tid & 15;
    const double thr = *thr_p;
    const float* wr = w + ((size_t)g * 16 + lr) * K_;
#pragma unroll
    for (int i = 0; i < 32; ++i) {
        const int k = i * 64 + c * 4;
        float4 v = *(const float4*)(wr + k);
        union { signed char ch[4]; u32 u; } p;
        p.ch[0] = (signed char)((fabs((double)v.x) > thr) ? (v.x > 0.0f ? 1 : -1) : 0);
        p.ch[1] = (signed char)((fabs((double)v.y) > thr) ? (v.y > 0.0f ? 1 : -1) : 0);
        p.ch[2] = (signed char)((fabs((double)v.z) > thr) ? (v.z > 0.0f ? 1 : -1) : 0);
        p.ch[3] = (signed char)((fabs((double)v.w) > thr) ? (v.w > 0.0f ? 1 : -1) : 0);
        *(u32*)&xs[lr][k] = p.u;
    }
    __syncthreads();
    u8* dst0 = Bp + (size_t)g * 32768;
#pragma unroll
    for (int j = 0; j < 8; ++j) {
        const int cell = j * 256 + tid;        // 0..2047
        const int kt   = cell >> 6;
        const int lane = cell & 63;
        const int lr2  = lane & 15;
        const int hi2  = lane >> 4;
        uint4 v = *(const uint4*)&xs[lr2][kt * 64 + hi2 * 16];
        *(uint4*)(dst0 + (size_t)kt * 1024 + lane * 16) = v;
    }
}

// ---------------------------------------------------------------------------
// prep_x: RMSNorm row -> i8 (per-row scale) stored fragment-direct in A'
// (same layout as B'). One block per row (v11 structure); LDS bounce; out
// writes 16B cells (neighboring row-blocks co-resident -> L2 merges).
// ---------------------------------------------------------------------------
__global__ __launch_bounds__(256)
void prep_x_kernel(const float* __restrict__ x, const float* __restrict__ gamma,
                   u8* __restrict__ Ap, float* __restrict__ scale)
{
    __shared__ float redsum[4];
    __shared__ float redmax[4];
    __shared__ alignas(16) uint2 xs8[256];     // 2KB: row's 2048 i8
    const int row = blockIdx.x;
    const int tid = threadIdx.x;
    const float* xr = x + (size_t)row * K_;
    float4 a = *(const float4*)(xr + tid * 8);
    float4 b = *(const float4*)(xr + tid * 8 + 4);
    float s = a.x*a.x + a.y*a.y + a.z*a.z + a.w*a.w
            + b.x*b.x + b.y*b.y + b.z*b.z + b.w*b.w;
#pragma unroll
    for (int o = 32; o; o >>= 1) s += __shfl_xor(s, o, 64);
    if ((tid & 63) == 0) redsum[tid >> 6] = s;
    __syncthreads();
    const float tot = (redsum[0] + redsum[1]) + (redsum[2] + redsum[3]);
    const float r = rsqrtf(tot * (1.0f / (float)K_) + 1.1920928955078125e-07f);
    float4 g0 = *(const float4*)(gamma + tid * 8);
    float4 g1 = *(const float4*)(gamma + tid * 8 + 4);
    float v[8];
    v[0] = a.x * r * g0.x;  v[1] = a.y * r * g0.y;
    v[2] = a.z * r * g0.z;  v[3] = a.w * r * g0.w;
    v[4] = b.x * r * g1.x;  v[5] = b.y * r * g1.y;
    v[6] = b.z * r * g1.z;  v[7] = b.w * r * g1.w;
    float m = 0.0f;
#pragma unroll
    for (int j = 0; j < 8; ++j) m = fmaxf(m, fabsf(v[j]));
#pragma unroll
    for (int o = 32; o; o >>= 1) m = fmaxf(m, __shfl_xor(m, o, 64));
    if ((tid & 63) == 0) redmax[tid >> 6] = m;
    __syncthreads();
    const float rowmax = fmaxf(fmaxf(redmax[0], redmax[1]), fmaxf(redmax[2], redmax[3]));
    const float inv = rowmax > 0.0f ? 127.0f / rowmax : 0.0f;
    union { signed char ch[8]; uint2 u; } p;
#pragma unroll
    for (int j = 0; j < 8; ++j) p.ch[j] = (signed char)__float2int_rn(v[j] * inv);
    xs8[tid] = p.u;
    __syncthreads();
    if (tid < 128) {
        // cell tid: kt = tid>>2, hi = tid&3; xs byte offset = tid*16.
        uint4 val = ((const uint4*)xs8)[tid];
        u8* dst = Ap + ((size_t)(row >> 4) * 32 + (tid >> 2)) * 1024
                     + ((tid & 3) * 16 + (row & 15)) * 16;
        *(uint4*)dst = val;
    }
    if (tid == 0) scale[row] = rowmax * (1.0f / 127.0f);
}

// ---------------------------------------------------------------------------
// GEMM  C[M,N] = scale[m] * (A_i8[M,K] @ W_i8[N,K]^T) + bias
// v13: NO LDS, NO BARRIERS. Operands pre-stored fragment-direct (A',B');
// each wave loads its fragments global->reg (one coalesced dwordx4 = one
// fragment), double-buffered sets, and runs MFMAs back-to-back. Reuse via
// L2 (A x4 waves, B x2 waves per block; unique A'+B' = 48MB lives in L3).
// Waves slip freely; compiler's counted vmcnt covers L2 latency (~1250cy
// of MFMA per set vs ~200-500cy latency). 8 waves (2Mx4N), wave out 128x64,
// block 256x256, grid 2048, XCD swizzle as v11. Regs ~240 (<=256 @ 2w/SIMD).
// ---------------------------------------------------------------------------
__global__ __launch_bounds__(512, 2)
void gemm_bt_kernel(const u8* __restrict__ Ap, const u8* __restrict__ Bp,
                    const float* __restrict__ bias, const float* __restrict__ scale,
                    float* __restrict__ C)
{
    const int tid  = threadIdx.x;
    const int lane = tid & 63;
    const int wid  = tid >> 6;
    const int wm   = wid >> 2;         // 0..1
    const int wn   = wid & 3;          // 0..3
    const int hi   = lane >> 4;        // 0..3

    // XCD-aware bijective swizzle: 2048 blocks % 8 == 0
    const int swz = (blockIdx.x & 7) * 256 + (blockIdx.x >> 3);
    const int gm0 = (swz >> 5) * 256;  // 64 M-tiles
    const int gn0 = (swz & 31) * 256;  // 32 N-tiles

    // fragment bases: group index g -> byte (g*32 + kt)*1024 + lane*16
    const u8* Abase = Ap + ((size_t)((gm0 + wm * 128) >> 4)) * 32768 + lane * 16;
    const u8* Bbase = Bp + ((size_t)((gn0 + wn * 64) >> 4)) * 32768 + lane * 16;

    i32x4 acc[8][4] = {};
    i32x4 aS0[8], aS1[8], bS0[4], bS1[4];

#define LOADSET(AS, BS, kt)                                                        \
    do {                                                                           \
        _Pragma("unroll") for (int mt = 0; mt < 8; ++mt)                           \
            AS[mt] = *(const i32x4*)(Abase + (size_t)mt * 32768 + (kt) * 1024);    \
        _Pragma("unroll") for (int nt = 0; nt < 4; ++nt)                           \
            BS[nt] = *(const i32x4*)(Bbase + (size_t)nt * 32768 + (kt) * 1024);    \
    } while (0)

#define MFMAS(AS, BS)                                                              \
    do {                                                                           \
        _Pragma("unroll") for (int nt = 0; nt < 4; ++nt)                           \
        _Pragma("unroll") for (int mt = 0; mt < 8; ++mt)                           \
            acc[mt][nt] = __builtin_amdgcn_mfma_i32_16x16x64_i8(                   \
                AS[mt], BS[nt], acc[mt][nt], 0, 0, 0);                             \
    } while (0)

    LOADSET(aS0, bS0, 0);
    LOADSET(aS1, bS1, 1);

    for (int i = 0; i < 16; ++i) {
        MFMAS(aS0, bS0);                       // waits (counted vmcnt) for set0
        if (i < 15) LOADSET(aS0, bS0, 2 * i + 2);
        MFMAS(aS1, bS1);
        if (i < 15) LOADSET(aS1, bS1, 2 * i + 3);
    }

    // ---- epilogue: C/D col=lane&15, row=hi*4+ri (v11-verified); dequant ----
    const int orow0 = gm0 + wm * 128 + hi * 4;
    const int ocol0 = gn0 + wn * 64 + (lane & 15);
    float bv[4];
#pragma unroll
    for (int n = 0; n < 4; ++n) bv[n] = bias[ocol0 + n * 16];
#pragma unroll
    for (int m = 0; m < 8; ++m) {
#pragma unroll
        for (int ri = 0; ri < 4; ++ri) {
            const int row = orow0 + m * 16 + ri;
            const float sc = scale[row];
#pragma unroll
            for (int n = 0; n < 4; ++n) {
                C[(size_t)row * N_ + (ocol0 + n * 16)] = (float)acc[m][n][ri] * sc + bv[n];
            }
        }
    }
#undef LOADSET
#undef MFMAS
}

// ---------------------------------------------------------------------------
// Workspace layout (bytes):
//   [0,8)                  : thr (double)
//   [1024, 9216)           : 1024 fp64 partials
//   [16384, +16MiB)        : B'  i8 fragment-direct [512 g][32 kt][64][16]
//   [+16MiB, +48MiB)       : A'  i8 fragment-direct [1024 g][32 kt][64][16]
//   [+48MiB, +64KiB)       : scale f32 [M]
// ---------------------------------------------------------------------------
extern "C" void kernel_launch(void* const* d_in, const int* in_sizes, int n_in,
                              void* d_out, int out_size, void* d_ws, size_t ws_size,
                              hipStream_t stream)
{
    const float* x     = (const float*)d_in[0];
    const float* w     = (const float*)d_in[1];
    const float* bias  = (const float*)d_in[2];
    const float* gamma = (const float*)d_in[3];
    float* out = (float*)d_out;

    char* ws = (char*)d_ws;
    double* thr      = (double*)(ws);
    double* partials = (double*)(ws + 1024);
    u8*     Bp       = (u8*)(ws + 16384);
    u8*     Ap       = (u8*)(ws + 16384 + NW_);
    float*  scale    = (float*)(ws + 16384 + NW_ + (size_t)M_ * K_);

    abssum_kernel <<<1024,  256,  0, stream>>>(w, partials);
    finalize_thr  <<<1,     1024, 0, stream>>>(partials, thr);
    prep_w_kernel <<<N_/16, 256,  0, stream>>>(w, thr, Bp);
    prep_x_kernel <<<M_,    256,  0, stream>>>(x, gamma, Ap, scale);
    gemm_bt_kernel<<<(M_/256)*(N_/256), 512, 0, stream>>>(Ap, Bp, bias, scale, out);
}

// Round 14
// 408.647 us; speedup vs baseline: 1.1847x; 1.1630x over previous
//
#include <hip/hip_runtime.h>

typedef unsigned short u16;
typedef unsigned int   u32;
typedef unsigned char  u8;
typedef __attribute__((ext_vector_type(4))) int   i32x4;

constexpr int B_ = 4, S_ = 4096, DIN_ = 2048, DOUT_ = 8192;
constexpr int M_ = B_ * S_;   // 16384
constexpr int N_ = DOUT_;     // 8192
constexpr int K_ = DIN_;      // 2048
constexpr size_t NW_ = (size_t)DOUT_ * DIN_;  // 16,777,216 weights

#define GPTR(p) ((const __attribute__((address_space(1))) void*)(p))
#define LPTR(p) ((__attribute__((address_space(3))) void*)(p))

#define SB0()   __builtin_amdgcn_sched_barrier(0)
#define BARB()  __builtin_amdgcn_s_barrier()                          // NO compiler fence
#define LGKM0() asm volatile("s_waitcnt lgkmcnt(0)" ::: "memory")
#define VM4()   asm volatile("s_waitcnt vmcnt(4)" ::: "memory")       // clobber REQUIRED:
#define VM0()   asm volatile("s_waitcnt vmcnt(0)" ::: "memory")       // blocks read-hoist past DMA retire

// ---------------------------------------------------------------------------
// Pass 1: deterministic fp64 abs-sum partials.
// ---------------------------------------------------------------------------
__global__ __launch_bounds__(256)
void abssum_kernel(const float* __restrict__ w, double* __restrict__ partials)
{
    const int tid = threadIdx.x;
    const float* base = w + (size_t)blockIdx.x * 16384 + tid * 4;
    double s = 0.0;
#pragma unroll
    for (int i = 0; i < 16; ++i) {
        float4 v = *(const float4*)(base + i * 1024);
        s += (double)fabsf(v.x) + (double)fabsf(v.y)
           + (double)fabsf(v.z) + (double)fabsf(v.w);
    }
#pragma unroll
    for (int o = 32; o; o >>= 1) s += __shfl_xor(s, o, 64);
    __shared__ double red[4];
    if ((tid & 63) == 0) red[tid >> 6] = s;
    __syncthreads();
    if (tid == 0) partials[blockIdx.x] = (red[0] + red[1]) + (red[2] + red[3]);
}

__global__ __launch_bounds__(1024)
void finalize_thr(const double* __restrict__ partials, double* __restrict__ thr)
{
    __shared__ double red[1024];
    const int tid = threadIdx.x;
    red[tid] = partials[tid];
    __syncthreads();
    for (int s = 512; s > 0; s >>= 1) {
        if (tid < s) red[tid] += red[tid + s];
        __syncthreads();
    }
    if (tid == 0) *thr = red[0] * (1.0 / (double)NW_);
}

// ---------------------------------------------------------------------------
// Pass 3: ternarize W -> i8 {-1,0,+1}; fp64 compare (threshold razor-thin).
// ---------------------------------------------------------------------------
__global__ __launch_bounds__(256)
void ternarize_kernel(const float* __restrict__ w, const double* __restrict__ thr_p,
                      signed char* __restrict__ wt)
{
    const double thr = *thr_p;
    const size_t i = ((size_t)blockIdx.x * 256 + threadIdx.x) * 4;
    float4 v = *(const float4*)(w + i);
    union { signed char c[4]; u32 u; } p;
    p.c[0] = (signed char)((fabs((double)v.x) > thr) ? (v.x > 0.0f ? 1 : -1) : 0);
    p.c[1] = (signed char)((fabs((double)v.y) > thr) ? (v.y > 0.0f ? 1 : -1) : 0);
    p.c[2] = (signed char)((fabs((double)v.z) > thr) ? (v.z > 0.0f ? 1 : -1) : 0);
    p.c[3] = (signed char)((fabs((double)v.w) > thr) ? (v.w > 0.0f ? 1 : -1) : 0);
    *(u32*)(wt + i) = p.u;
}

// ---------------------------------------------------------------------------
// Pass 4: RMSNorm rows of x (fp32) -> i8 xn with per-row scale (exact i32
// matmul vs ternary weights; only activation quantization contributes error).
// ---------------------------------------------------------------------------
__global__ __launch_bounds__(256)
void rmsnorm_q_kernel(const float* __restrict__ x, const float* __restrict__ gamma,
                      signed char* __restrict__ xn, float* __restrict__ scale)
{
    const int row = blockIdx.x;
    const int tid = threadIdx.x;
    const float* xr = x + (size_t)row * K_;
    float4 a = *(const float4*)(xr + tid * 8);
    float4 b = *(const float4*)(xr + tid * 8 + 4);
    float s = a.x*a.x + a.y*a.y + a.z*a.z + a.w*a.w
            + b.x*b.x + b.y*b.y + b.z*b.z + b.w*b.w;
#pragma unroll
    for (int o = 32; o; o >>= 1) s += __shfl_xor(s, o, 64);
    __shared__ float redsum[4];
    __shared__ float redmax[4];
    if ((tid & 63) == 0) redsum[tid >> 6] = s;
    __syncthreads();
    const float tot = (redsum[0] + redsum[1]) + (redsum[2] + redsum[3]);
    const float r = rsqrtf(tot * (1.0f / (float)K_) + 1.1920928955078125e-07f);
    float4 g0 = *(const float4*)(gamma + tid * 8);
    float4 g1 = *(const float4*)(gamma + tid * 8 + 4);
    float v[8];
    v[0] = a.x * r * g0.x;  v[1] = a.y * r * g0.y;
    v[2] = a.z * r * g0.z;  v[3] = a.w * r * g0.w;
    v[4] = b.x * r * g1.x;  v[5] = b.y * r * g1.y;
    v[6] = b.z * r * g1.z;  v[7] = b.w * r * g1.w;
    float m = 0.0f;
#pragma unroll
    for (int j = 0; j < 8; ++j) m = fmaxf(m, fabsf(v[j]));
#pragma unroll
    for (int o = 32; o; o >>= 1) m = fmaxf(m, __shfl_xor(m, o, 64));
    if ((tid & 63) == 0) redmax[tid >> 6] = m;
    __syncthreads();
    const float rowmax = fmaxf(fmaxf(redmax[0], redmax[1]), fmaxf(redmax[2], redmax[3]));
    const float inv = rowmax > 0.0f ? 127.0f / rowmax : 0.0f;
    union { signed char c[8]; uint2 u; } p;
#pragma unroll
    for (int j = 0; j < 8; ++j) p.c[j] = (signed char)__float2int_rn(v[j] * inv);
    *(uint2*)(xn + (size_t)row * K_ + tid * 8) = p.u;
    if (tid == 0) scale[row] = rowmax * (1.0f / 127.0f);
}

// ---------------------------------------------------------------------------
// Pass 5: GEMM  C[M,N] = scale[m] * (xn_i8[M,K] @ wt_i8[N,K]^T) + bias
// v14 = v11 with the COMPILER FENCE REMOVED (the m201 mechanism):
//  - barriers are __builtin_amdgcn_s_barrier() (HW sync, no memory clobber)
//    so the scheduler can hoist next-phase ds_reads into the MFMA cluster
//    (reads drain UNDER MFMA instead of serially in front of it);
//  - sched_barrier(0) only after LGKM0/VM (rule 18: pin MFMA after the wait);
//  - stage WAR margins widened to >=2 phases (A0 both halves at p3, A1 both
//    at p7) so a stage hoisted past one barrier still executes two barriers
//    after the conflicting reads' lgkm0:   stage@p -> after SB0@p-1 ->
//    after BARB@p-2-post -> all waves' LGKM0@p-2 done -> reads retired.
//  - VM4/VM0 keep "memory": blocks buf-switch reads from hoisting above the
//    DMA retire point AND pins gload issue order (vmcnt ledger intact).
//
//   phase: reads (buf)    stage                       MFMA
//   p0   : a0,b0 (buf0)   B1h0 -> buf1@kt1            Q0(T0)
//   p1   : a1    (buf0)   B1h1 -> buf1@kt1            Q2(T0)
//   p2   : b1    (buf0)   --                          Q1(T0)
//   p3   : --             A0h0+A0h1 -> buf0@ktn0      Q3(T0)  VM4*
//   p4   : a0,b0 (buf1)   B0h0 -> buf0@ktn0           Q0(T1)
//   p5   : a1    (buf1)   B0h1 -> buf0@ktn0           Q2(T1)
//   p6   : b1    (buf1)   --                          Q1(T1)
//   p7   : --             A1h0+A1h1 -> buf1@ktn1      Q3(T1)  VM4*
// Ledger: prologue 12 gloads, VM4 retires A0,B0 (8). p3: 4+4+4=12 out ->
// VM4 retires A1+B1 (8), keeps A0@ktn0. p7: 12 -> retires A0+B0, keeps A1.
// Tail i=7: p3 VM0 (all outstanding staged >=3 phases earlier); no ktn stages.
// ---------------------------------------------------------------------------
__global__ __launch_bounds__(512, 2)
void gemm_bt_kernel(const u8* __restrict__ A, const u8* __restrict__ Bt,
                    const float* __restrict__ bias, const float* __restrict__ scale,
                    float* __restrict__ C)
{
    __shared__ alignas(16) u8 sm[131072];   // 128 KiB
    const char* smc = (const char*)sm;

    const int tid  = threadIdx.x;
    const int lane = tid & 63;
    const int wid  = tid >> 6;
    const int wm   = wid >> 2;         // 0..1
    const int wn   = wid & 3;          // 0..3
    const int hi   = lane >> 4;        // 0..3

    // XCD-aware bijective swizzle: 2048 blocks % 8 == 0
    const int swz = (blockIdx.x & 7) * 256 + (blockIdx.x >> 3);
    const int gm0 = (swz >> 5) * 256;  // 64 M-tiles
    const int gn0 = (swz & 31) * 256;  // 32 N-tiles

    // ---- staging geometry (linear LDS dest, pre-swizzled global source) ----
    const int lr8   = lane >> 3;
    const int cswel = ((lane & 7) ^ lr8) * 16;         // swizzled k-elem offset
    const int rbase = wid * 8 + lr8;                   // 0..63
    const u8* gAr  = A  + (size_t)(gm0 + rbase) * K_ + cswel;
    const u8* gBr  = Bt + (size_t)(gn0 + rbase) * K_ + cswel;
    const u8* gAr2 = gAr + 262144;                     // +128 rows
    const u8* gBr2 = gBr + 262144;

    // one stage call = 128 rows x 128 B = 2 gload_lds(16B)/thread
    auto STAGE = [&](const u8* g, int ldsb, int kt) {
        u8* d = sm + ldsb + wid * 1024 + lane * 16;
        const u8* s = g + kt;
        __builtin_amdgcn_global_load_lds(GPTR(s),             LPTR(d),        16, 0, 0);
        __builtin_amdgcn_global_load_lds(GPTR(s + 64 * 2048), LPTR(d + 8192), 16, 0, 0);
    };

    // ---- read geometry (v11's measured-zero-conflict pattern) ----
    const int c0 = ((hi ^ (lane & 7)) << 4);
    const int rowbyteA = (wm * 128 + (lane & 15)) * 128;
    const int rowbyteB = (wn * 64  + (lane & 15)) * 128;

#define RA(bufr, m, kk) (*(const i32x4*)(smc + (bufr)*32768 + rowbyteA + (m)*2048 + (c0 ^ ((kk) << 6))))
#define RB(bufr, n, kk) (*(const i32x4*)(smc + 65536 + (bufr)*32768 + rowbyteB + (n)*2048 + (c0 ^ ((kk) << 6))))

    i32x4 acc[8][4] = {};
    i32x4 a0[4][2], a1[4][2], b0[2][2], b1[2][2];

#define MFMA_BLK(AF, BF, MO, NO)                                                   \
    do {                                                                           \
        _Pragma("unroll") for (int kk = 0; kk < 2; ++kk)                           \
        _Pragma("unroll") for (int m = 0; m < 4; ++m)                              \
        _Pragma("unroll") for (int n = 0; n < 2; ++n)                              \
            acc[m + MO][n + NO] = __builtin_amdgcn_mfma_i32_16x16x64_i8(           \
                AF[m][kk], BF[n][kk], acc[m + MO][n + NO], 0, 0, 0);               \
    } while (0)

#define READ_A0B0(bufr)                                                            \
    do {                                                                           \
        _Pragma("unroll") for (int m = 0; m < 4; ++m) {                            \
            a0[m][0] = RA(bufr, m, 0); a0[m][1] = RA(bufr, m, 1); }                \
        _Pragma("unroll") for (int n = 0; n < 2; ++n) {                            \
            b0[n][0] = RB(bufr, n, 0); b0[n][1] = RB(bufr, n, 1); }                \
    } while (0)
#define READ_A1(bufr)                                                              \
    do { _Pragma("unroll") for (int m = 0; m < 4; ++m) {                           \
            a1[m][0] = RA(bufr, m + 4, 0); a1[m][1] = RA(bufr, m + 4, 1); } } while (0)
#define READ_B1(bufr)                                                              \
    do { _Pragma("unroll") for (int n = 0; n < 2; ++n) {                           \
            b1[n][0] = RB(bufr, n + 2, 0); b1[n][1] = RB(bufr, n + 2, 1); } } while (0)

#define PRIO_MFMA(AF, BF, MO, NO)                                                  \
    do { __builtin_amdgcn_s_setprio(1); MFMA_BLK(AF, BF, MO, NO);                  \
         __builtin_amdgcn_s_setprio(0); } while (0)

    // phase tail/head: HW barrier (no fence) + wait + rule-18 pin
#define PH_MID()  do { BARB(); LGKM0(); SB0(); } while (0)

    // ---- prologue: buf0 A+B @0, buf1 A @128; retire buf0 ----
    STAGE(gAr,  0,     0);
    STAGE(gAr2, 16384, 0);
    STAGE(gBr,  65536, 0);
    STAGE(gBr2, 81920, 0);
    STAGE(gAr,  32768, 128);
    STAGE(gAr2, 49152, 128);
    VM4(); SB0(); BARB();

    for (int i = 0; i < 8; ++i) {
        const int kt1  = i * 256 + 128;
        const int ktn0 = i * 256 + 256;     // buf0 next K-tile
        const int ktn1 = i * 256 + 384;     // buf1 next K-tile
        const bool f = (i < 7);

        // ---- p0: reads a0,b0(buf0) | stage B1h0@kt1 | Q0(T0) ----
        READ_A0B0(0);
        STAGE(gBr, 98304, kt1);
        PH_MID();
        PRIO_MFMA(a0, b0, 0, 0);
        BARB();

        // ---- p1: reads a1(buf0) | stage B1h1@kt1 | Q2(T0) ----
        READ_A1(0);
        STAGE(gBr2, 114688, kt1);
        PH_MID();
        PRIO_MFMA(a1, b0, 4, 0);
        BARB();

        // ---- p2: reads b1(buf0) | Q1(T0) ----
        READ_B1(0);
        PH_MID();
        PRIO_MFMA(a0, b1, 0, 2);
        BARB();

        // ---- p3: stage A0 both halves @ktn0 | Q3(T0) | VM ----
        if (f) { STAGE(gAr, 0, ktn0); STAGE(gAr2, 16384, ktn0); }
        PH_MID();
        PRIO_MFMA(a1, b1, 4, 2);
        if (f) { VM4(); } else { VM0(); }
        SB0(); BARB();

        // ---- p4: reads a0,b0(buf1) | stage B0h0@ktn0 | Q0(T1) ----
        READ_A0B0(1);
        if (f) STAGE(gBr, 65536, ktn0);
        PH_MID();
        PRIO_MFMA(a0, b0, 0, 0);
        BARB();

        // ---- p5: reads a1(buf1) | stage B0h1@ktn0 | Q2(T1) ----
        READ_A1(1);
        if (f) STAGE(gBr2, 81920, ktn0);
        PH_MID();
        PRIO_MFMA(a1, b0, 4, 0);
        BARB();

        // ---- p6: reads b1(buf1) | Q1(T1) ----
        READ_B1(1);
        PH_MID();
        PRIO_MFMA(a0, b1, 0, 2);
        BARB();

        // ---- p7: stage A1 both halves @ktn1 | Q3(T1) | VM ----
        if (f) { STAGE(gAr, 32768, ktn1); STAGE(gAr2, 49152, ktn1); }
        PH_MID();
        PRIO_MFMA(a1, b1, 4, 2);
        if (f) { VM4(); SB0(); }
        BARB();
    }

    // ---- epilogue: C/D col=lane&15, row=hi*4+ri; dequant + bias ----
    const int orow0 = gm0 + wm * 128 + hi * 4;
    const int ocol0 = gn0 + wn * 64 + (lane & 15);
    float bv[4];
#pragma unroll
    for (int n = 0; n < 4; ++n) bv[n] = bias[ocol0 + n * 16];
#pragma unroll
    for (int m = 0; m < 8; ++m) {
#pragma unroll
        for (int ri = 0; ri < 4; ++ri) {
            const int row = orow0 + m * 16 + ri;
            const float sc = scale[row];
#pragma unroll
            for (int n = 0; n < 4; ++n) {
                C[(size_t)row * N_ + (ocol0 + n * 16)] = (float)acc[m][n][ri] * sc + bv[n];
            }
        }
    }
#undef RA
#undef RB
#undef MFMA_BLK
#undef READ_A0B0
#undef READ_A1
#undef READ_B1
#undef PRIO_MFMA
#undef PH_MID
}

// ---------------------------------------------------------------------------
// Workspace layout (bytes):
//   [0,8)                    : thr (double)
//   [1024, 9216)             : 1024 fp64 partials
//   [16384, +16MiB)          : wt    i8 [N=8192][K=2048]
//   [+16MiB, +48MiB)         : xn    i8 [M=16384][K=2048]
//   [+48MiB, +48MiB+64KiB)   : scale f32 [M]
// ---------------------------------------------------------------------------
extern "C" void kernel_launch(void* const* d_in, const int* in_sizes, int n_in,
                              void* d_out, int out_size, void* d_ws, size_t ws_size,
                              hipStream_t stream)
{
    const float* x     = (const float*)d_in[0];
    const float* w     = (const float*)d_in[1];
    const float* bias  = (const float*)d_in[2];
    const float* gamma = (const float*)d_in[3];
    float* out = (float*)d_out;

    char* ws = (char*)d_ws;
    double*      thr      = (double*)(ws);
    double*      partials = (double*)(ws + 1024);
    signed char* wt       = (signed char*)(ws + 16384);
    signed char* xn       = (signed char*)(ws + 16384 + NW_);
    float*       scale    = (float*)(ws + 16384 + NW_ + (size_t)M_ * K_);

    abssum_kernel   <<<1024,  256,  0, stream>>>(w, partials);
    finalize_thr    <<<1,     1024, 0, stream>>>(partials, thr);
    ternarize_kernel<<<16384, 256,  0, stream>>>(w, thr, wt);
    rmsnorm_q_kernel<<<M_,    256,  0, stream>>>(x, gamma, xn, scale);
    gemm_bt_kernel  <<<(M_/256)*(N_/256), 512, 0, stream>>>((const u8*)xn, (const u8*)wt, bias, scale, out);
}